// Round 11
// baseline (129.238 us; speedup 1.0000x reference)
//
#include <hip/hip_runtime.h>

#define N_NODES   50000
#define N_EDGES   800000
#define IN_DIM    100
#define HIDDEN    16
#define N_CLASSES 40

// Bucketing geometry: bucket = dst >> 6 (64 nodes per bucket)
#define BSHIFT 6
#define NPB    64                        // nodes per bucket
#define NBKT   782                       // ceil(N_NODES / NPB)
#define PB     256                       // partition blocks/regions
#define EPB    3125                      // edges per region (256*3125 = 800000)
#define EPT    7                         // max edges in regs/thread (ceil(3125/512))
#define CAP    1792                      // per-bucket capacity (mean 1024, sd 32 -> +24sd)
#define GEMMB  782                       // gemm tiles of 64 rows

// K1 LDS union:
//  partition: cnt[782]@0(3200) | lcur@3200(3200) | wpre[8]@6400
//             | staged int2[3125]@8448 .. 33448
//  gemm:      sX[64*100]@0 .. 25600 | sW[1600]@25600 .. 32000
#define K1_LDS 33456

// ---------------------------------------------------------------------------
// K1: blocks [0,PB) partition the edge list (edges held in REGISTERS between
// count and scatter -> single global read); blocks [PB, PB+GEMMB) compute
// y1 = X @ W1 concurrently. Verified rounds 7/10.
// BTt transposed: BTt[k*PB + b] = start of bucket k's run in region b.
// Payload: {src | dst_low6 << 16, val}.
// ---------------------------------------------------------------------------
__global__ __launch_bounds__(512) void build_and_gemm(const int* __restrict__ src,
                                                      const int* __restrict__ dst,
                                                      const float* __restrict__ val,
                                                      const float* __restrict__ X,
                                                      const float* __restrict__ W,
                                                      int* __restrict__ BTt,
                                                      int2* __restrict__ binned,
                                                      float* __restrict__ Y) {
    __shared__ __align__(16) char smem[K1_LDS];
    const int tid = threadIdx.x;

    if (blockIdx.x < PB) {
        // ---------------- partition path ----------------
        int*  cnt    = (int*)smem;
        int*  lcur   = (int*)(smem + 3200);
        int*  wpre   = (int*)(smem + 6400);
        int2* staged = (int2*)(smem + 8448);
        const int b = blockIdx.x, e0 = b * EPB;
        const int lane = tid & 63, w = tid >> 6;      // 8 waves

        for (int k = tid; k < NBKT; k += 512) cnt[k] = 0;
        __syncthreads();

        // single global read: hold edges in registers, count buckets
        int pk[EPT], ps[EPT]; float pv[EPT];
#pragma unroll
        for (int q = 0; q < EPT; ++q) {
            const int i = tid + q * 512;
            if (i < EPB) {
                const int e = e0 + i;
                const int d = dst[e];
                pk[q] = d >> BSHIFT;
                ps[q] = src[e] | ((d & (NPB - 1)) << 16);
                pv[q] = val[e];
                atomicAdd(&cnt[pk[q]], 1);
            } else pk[q] = -1;
        }
        __syncthreads();

        // exclusive scan over 782 buckets: 2 buckets/thread + shfl wave-scan
        const int k0 = 2 * tid, k1 = 2 * tid + 1;
        const int a  = (k0 < NBKT) ? cnt[k0] : 0;
        const int bb = (k1 < NBKT) ? cnt[k1] : 0;
        const int s  = a + bb;
        int x = s;
#pragma unroll
        for (int d = 1; d < 64; d <<= 1) {
            const int y = __shfl_up(x, d, 64);
            if (lane >= d) x += y;
        }
        if (lane == 63) wpre[w] = x;
        __syncthreads();
        int add = 0;
        for (int i = 0; i < w; ++i) add += wpre[i];
        const int excl = add + x - s;
        if (k0 < NBKT) { lcur[k0] = excl;     BTt[k0 * PB + b] = excl; }
        if (k1 < NBKT) { lcur[k1] = excl + a; BTt[k1 * PB + b] = excl + a; }
        if (tid == 0)  BTt[NBKT * PB + b] = EPB;
        __syncthreads();

        // scatter from registers into LDS, bucket-grouped
#pragma unroll
        for (int q = 0; q < EPT; ++q) {
            if (pk[q] >= 0) {
                const int pos = atomicAdd(&lcur[pk[q]], 1);
                staged[pos] = make_int2(ps[q], __float_as_int(pv[q]));
            }
        }
        __syncthreads();

        // linear coalesced copy-out
        for (int i = tid; i < EPB; i += 512)
            binned[e0 + i] = staged[i];
    } else {
        // ---------------- gemm path: 64 rows, thread = (row, float2-col) ----
        float* sX = (float*)smem;
        float* sW = (float*)(smem + 25600);
        const int b2   = blockIdx.x - PB;
        const int row0 = b2 * 64;
        const int nrows = min(64, N_NODES - row0);

        const float4* W4 = (const float4*)W;
        float4* sW4 = (float4*)sW;
        for (int i = tid; i < (IN_DIM * HIDDEN) / 4; i += 512) sW4[i] = W4[i];
        const float4* X4 = (const float4*)(X + (size_t)row0 * IN_DIM);
        float4* sX4 = (float4*)sX;
        const int nf4 = nrows * (IN_DIM / 4);
        for (int i = tid; i < nf4; i += 512) sX4[i] = X4[i];
        __syncthreads();

        const int r = tid >> 3, hh = tid & 7;
        if (r >= nrows) return;
        float2 acc = make_float2(0.f, 0.f);
        const float* xr = &sX[r * IN_DIM];
#pragma unroll
        for (int kk = 0; kk < IN_DIM; ++kk) {
            const float xk = xr[kk];
            const float2 wv = *(const float2*)&sW[kk * HIDDEN + hh * 2];
            acc.x = fmaf(xk, wv.x, acc.x);
            acc.y = fmaf(xk, wv.y, acc.y);
        }
        *(float2*)&Y[(size_t)(row0 + r) * HIDDEN + hh * 2] = acc;
    }
}

// ---------------------------------------------------------------------------
// Shared per-bucket in-LDS sort preamble (round-10 verified, hist fused into
// the stage loop). After it: srt[0..tot) node-sorted; cnt[g]=deg; cur[g]=end.
// ---------------------------------------------------------------------------
__device__ __forceinline__ void bucket_sort_lds(const int* __restrict__ BTt,
                                                const int2* __restrict__ binned,
                                                int k, int tid,
                                                int2* raw, int2* srt,
                                                int* cnt, int* cur, int* aux) {
    const int lane = tid & 63, w = tid >> 6;
    if (tid < NPB) cnt[tid] = 0;

    // thread t owns region t's run for bucket k (coalesced BTt reads)
    const int rs = BTt[k * PB + tid];
    const int re = BTt[(k + 1) * PB + tid];
    const int len = re - rs;
    int x = len;
#pragma unroll
    for (int d = 1; d < 64; d <<= 1) {
        const int y = __shfl_up(x, d, 64);
        if (lane >= d) x += y;
    }
    if (lane == 63) aux[w] = x;
    __syncthreads();                       // cnt zeroed + aux visible
    int add = 0;
    for (int i = 0; i < w; ++i) add += aux[i];

    // single global read: stage runs into LDS, node-hist FUSED into the loop
    int o = add + x - len;
    const int2* rb = binned + (size_t)tid * EPB;
    for (int p = rs; p < re; ++p, ++o) {
        const int2 e = rb[p];
        raw[o] = e;
        atomicAdd(&cnt[(e.x >> 16) & (NPB - 1)], 1);
    }
    __syncthreads();

    // wave scan over 64 node counts
    if (tid < NPB) {
        const int v = cnt[tid];
        int xx = v;
#pragma unroll
        for (int d = 1; d < 64; d <<= 1) {
            const int y = __shfl_up(xx, d, 64);
            if (tid >= d) xx += y;
        }
        cur[tid] = xx - v;
    }
    __syncthreads();

    // rank-scatter LDS -> LDS
    const int tot = aux[0] + aux[1] + aux[2] + aux[3];
    for (int i = tid; i < tot; i += 256) {
        const int2 e = raw[i];
        const int pos = atomicAdd(&cur[(e.x >> 16) & (NPB - 1)], 1);
        srt[pos] = make_int2(e.x & 0xFFFF, e.y);
    }
    __syncthreads();
}

// 4-lane float4 CSR gather from LDS srt, unroll x4 (4 global loads in flight).
__device__ __forceinline__ float4 gather4(const int2* srt, int beg, int deg,
                                          const float4* X4, int q) {
    float4 a = make_float4(0.f, 0.f, 0.f, 0.f);
    const int end = beg + deg;
    int p = beg;
    for (; p + 4 <= end; p += 4) {
        const int2 e0 = srt[p];
        const int2 e1 = srt[p + 1];
        const int2 e2 = srt[p + 2];
        const int2 e3 = srt[p + 3];
        const float4 x0 = X4[(size_t)e0.x * 4 + q];
        const float4 x1 = X4[(size_t)e1.x * 4 + q];
        const float4 x2 = X4[(size_t)e2.x * 4 + q];
        const float4 x3 = X4[(size_t)e3.x * 4 + q];
        const float v0 = __int_as_float(e0.y), v1 = __int_as_float(e1.y);
        const float v2 = __int_as_float(e2.y), v3 = __int_as_float(e3.y);
        a.x = fmaf(v0, x0.x, a.x); a.y = fmaf(v0, x0.y, a.y);
        a.z = fmaf(v0, x0.z, a.z); a.w = fmaf(v0, x0.w, a.w);
        a.x = fmaf(v1, x1.x, a.x); a.y = fmaf(v1, x1.y, a.y);
        a.z = fmaf(v1, x1.z, a.z); a.w = fmaf(v1, x1.w, a.w);
        a.x = fmaf(v2, x2.x, a.x); a.y = fmaf(v2, x2.y, a.y);
        a.z = fmaf(v2, x2.z, a.z); a.w = fmaf(v2, x2.w, a.w);
        a.x = fmaf(v3, x3.x, a.x); a.y = fmaf(v3, x3.y, a.y);
        a.z = fmaf(v3, x3.z, a.z); a.w = fmaf(v3, x3.w, a.w);
    }
    for (; p < end; ++p) {
        const int2 e = srt[p];
        const float v = __int_as_float(e.y);
        const float4 xv = X4[(size_t)e.x * 4 + q];
        a.x = fmaf(v, xv.x, a.x); a.y = fmaf(v, xv.y, a.y);
        a.z = fmaf(v, xv.z, a.z); a.w = fmaf(v, xv.w, a.w);
    }
    return a;
}

// ---------------------------------------------------------------------------
// K2: per-bucket sort (in LDS) + fused gather1: z1 = relu(A @ y1).
// 29.2 KB LDS -> 5 blocks/CU.
// ---------------------------------------------------------------------------
__global__ __launch_bounds__(256) void sort_gather1(const int* __restrict__ BTt,
                                                    const int2* __restrict__ binned,
                                                    const float* __restrict__ Yin,
                                                    float* __restrict__ Z) {
    __shared__ int2 raw[CAP];          // 14 KB
    __shared__ int2 srt[CAP];          // 14 KB
    __shared__ int  cnt[NPB], cur[NPB], aux[4];
    const int tid = threadIdx.x, k = blockIdx.x;

    bucket_sort_lds(BTt, binned, k, tid, raw, srt, cnt, cur, aux);

    const int g = tid >> 2, q = tid & 3;
    const int node = k * NPB + g;
    const int deg = cnt[g];
    const int beg = cur[g] - deg;
    float4 a = gather4(srt, beg, deg, (const float4*)Yin, q);
    if (node < N_NODES) {
        a.x = fmaxf(a.x, 0.f); a.y = fmaxf(a.y, 0.f);
        a.z = fmaxf(a.z, 0.f); a.w = fmaxf(a.w, 0.f);
        ((float4*)Z)[(size_t)node * 4 + q] = a;
    }
}

// ---------------------------------------------------------------------------
// K3: per-bucket sort (in LDS) + gather2 (z2 = A @ z1) + width-4 shfl
// quad-exchange (replaces LDS transpose + barrier) + log_softmax(z2 @ W2).
// 4 lanes/node; lane q owns classes [10q, 10q+10); width-4 shfl reduce.
// 31.8 KB LDS -> 5 blocks/CU.
// ---------------------------------------------------------------------------
__global__ __launch_bounds__(256) void sort_gather_out(const int* __restrict__ BTt,
                                                       const int2* __restrict__ binned,
                                                       const float* __restrict__ Zin,
                                                       const float* __restrict__ W2,
                                                       float* __restrict__ out) {
    __shared__ int2  raw[CAP];                 // 14 KB
    __shared__ int2  srt[CAP];                 // 14 KB
    __shared__ int   cnt[NPB], cur[NPB], aux[4];
    __shared__ float sW2[HIDDEN * N_CLASSES];  // 2.56 KB
    const int tid = threadIdx.x, k = blockIdx.x;

    for (int i = tid; i < HIDDEN * N_CLASSES; i += 256) sW2[i] = W2[i];

    bucket_sort_lds(BTt, binned, k, tid, raw, srt, cnt, cur, aux);

    const int g = tid >> 2, q = tid & 3;
    const int node = k * NPB + g;
    const int deg = cnt[g];
    const int beg = cur[g] - deg;
    const float4 a = gather4(srt, beg, deg, (const float4*)Zin, q);

    if (node >= N_NODES) return;   // whole 4-lane group uniform -> shfl safe

    // width-4 quad exchange: z[16] = this node's full z2 row
    float z[HIDDEN];
#pragma unroll
    for (int qq = 0; qq < 4; ++qq) {
        float4 b;
        b.x = __shfl(a.x, qq, 4);
        b.y = __shfl(a.y, qq, 4);
        b.z = __shfl(a.z, qq, 4);
        b.w = __shfl(a.w, qq, 4);
        z[4 * qq + 0] = b.x; z[4 * qq + 1] = b.y;
        z[4 * qq + 2] = b.z; z[4 * qq + 3] = b.w;
    }

    float oc[10];
#pragma unroll
    for (int c = 0; c < 10; ++c) oc[c] = 0.f;
#pragma unroll
    for (int kk = 0; kk < HIDDEN; ++kk) {
        const float zk = z[kk];
        const float* wr = &sW2[kk * N_CLASSES + q * 10];
#pragma unroll
        for (int c = 0; c < 10; ++c) oc[c] = fmaf(zk, wr[c], oc[c]);
    }
    float m = oc[0];
#pragma unroll
    for (int c = 1; c < 10; ++c) m = fmaxf(m, oc[c]);
#pragma unroll
    for (int d = 1; d < 4; d <<= 1) m = fmaxf(m, __shfl_xor(m, d, 4));
    float se = 0.f;
#pragma unroll
    for (int c = 0; c < 10; ++c) se += __expf(oc[c] - m);
#pragma unroll
    for (int d = 1; d < 4; d <<= 1) se += __shfl_xor(se, d, 4);
    const float lse = m + __logf(se);

    float* orow = out + (size_t)node * N_CLASSES + q * 10;
#pragma unroll
    for (int c = 0; c < 10; ++c) orow[c] = oc[c] - lse;
}

extern "C" void kernel_launch(void* const* d_in, const int* in_sizes, int n_in,
                              void* d_out, int out_size, void* d_ws, size_t ws_size,
                              hipStream_t stream) {
    const float* features = (const float*)d_in[0];  // [50000,100]
    const int*   edge_src = (const int*)d_in[1];    // [800000]
    const int*   edge_dst = (const int*)d_in[2];    // [800000]
    const float* edge_val = (const float*)d_in[3];  // [800000]
    const float* W1       = (const float*)d_in[4];  // [100,16]
    const float* W2       = (const float*)d_in[5];  // [16,40]
    float*       out      = (float*)d_out;          // [50000,40]

    char* base = (char*)d_ws;
    const size_t HNB = (size_t)N_NODES * HIDDEN * sizeof(float);     // 3.2 MB
    float* y1     = (float*)(base);
    float* z1     = (float*)(base + HNB);
    int2*  binned = (int2*) (base + 2 * HNB);                        // 6.4 MB
    int*   BTt    = (int*)  (base + 2 * HNB + (size_t)N_EDGES * 8);  // ~802 KB

    // K1: partition (blocks 0..255) || gemm y1 = X@W1 (blocks 256..1037)
    build_and_gemm<<<PB + GEMMB, 512, 0, stream>>>(edge_src, edge_dst, edge_val,
                                                   features, W1, BTt, binned, y1);
    // K2: in-LDS bucket sort + z1 = relu(A @ y1)
    sort_gather1<<<NBKT, 256, 0, stream>>>(BTt, binned, y1, z1);
    // K3: in-LDS bucket sort + z2 = A @ z1 + log_softmax(z2 @ W2)
    sort_gather_out<<<NBKT, 256, 0, stream>>>(BTt, binned, z1, W2, out);
}